// Round 2
// baseline (701.978 us; speedup 1.0000x reference)
//
#include <hip/hip_runtime.h>
#include <hip/hip_bf16.h>

typedef __bf16 bf16_t;
typedef __bf16 bf16x8 __attribute__((ext_vector_type(8)));
typedef float f32x4 __attribute__((ext_vector_type(4)));

#define N_NODES 1000000
#define D_FEAT 128
#define N_GRAPHS 8192
#define U_DIM 64
#define HIDDEN 256
#define GDIM 128
#define IN_DIM 576

// workspace layout (bytes)
#define OFF_STARTS 0
#define OFF_PACKED 65536
#define OFF_W1T (OFF_PACKED + N_GRAPHS * IN_DIM * 2)   // bf16 packed input
#define OFF_W2T (OFF_W1T + HIDDEN * IN_DIM * 2)        // bf16 W1^T

// ---------------------------------------------------------------------------
// prep: boundaries from sorted batch (int32), pack u (fp32->bf16),
// transpose W1/W2 to k-innermost bf16.
// grid = 2048 (u) + 3907 (boundaries) + 576 (W1t) + 128 (W2t) = 6659
// ---------------------------------------------------------------------------
__global__ __launch_bounds__(256) void prep_kernel(
    const float* __restrict__ u, const int* __restrict__ batch,
    const float* __restrict__ W1, const float* __restrict__ W2,
    int* __restrict__ starts, bf16_t* __restrict__ packed,
    bf16_t* __restrict__ W1t, bf16_t* __restrict__ W2t)
{
    int b = blockIdx.x;
    int t = threadIdx.x;
    if (b < 2048) {
        int idx = b * 256 + t;            // 0..524287
        int g = idx >> 6, j = idx & 63;
        packed[(size_t)g * IN_DIM + j] = (bf16_t)u[idx];
    } else if (b < 2048 + 3907) {
        int i = (b - 2048) * 256 + t;
        if (i < N_NODES) {
            int bb = batch[i];
            int prev = (i == 0) ? -1 : batch[i - 1];
            for (int g = prev + 1; g <= bb; ++g) starts[g] = i;
            if (i == N_NODES - 1) {
                for (int g = bb + 1; g <= N_GRAPHS; ++g) starts[g] = N_NODES;
            }
        }
    } else if (b < 2048 + 3907 + 576) {
        // W1t[n][k] = W1[k][n]; W1 is [576][256] fp32
        int idx = (b - 5955) * 256 + t;   // coalesced read
        int k = idx >> 8, n = idx & 255;
        W1t[(size_t)n * IN_DIM + k] = (bf16_t)W1[idx];
    } else {
        // W2t[n][k] = W2[k][n]; W2 is [256][128] fp32
        int idx = (b - 6531) * 256 + t;
        int k = idx >> 7, n = idx & 127;
        W2t[(size_t)n * HIDDEN + k] = (bf16_t)W2[idx];
    }
}

// ---------------------------------------------------------------------------
// aggregate: one block per graph. 256 threads = 8 row-groups x 32 feat-chunks
// (4 fp32 each = 16B vector loads), 2-row unroll. fp32 accumulate; LDS
// cross-group reduce. Writes mean/std/max/min (bf16) to packed[g][64:576].
// ---------------------------------------------------------------------------
__global__ __launch_bounds__(256) void aggregate_kernel(
    const float* __restrict__ x, const int* __restrict__ starts,
    bf16_t* __restrict__ packed)
{
    int g = blockIdx.x;
    int t = threadIdx.x;
    int grp = t >> 5;          // 0..7 row group
    int fb = (t & 31) * 4;     // feature base (0..124)

    int s = starts[g];
    int e = starts[g + 1];

    float sum[4], sq[4], mx[4], mn[4];
#pragma unroll
    for (int j = 0; j < 4; ++j) {
        sum[j] = 0.f; sq[j] = 0.f; mx[j] = -3.4e38f; mn[j] = 3.4e38f;
    }

    for (int r = s + grp; r < e; r += 16) {
        float4 v0 = *(const float4*)(x + (size_t)r * D_FEAT + fb);
        int r2 = r + 8;
        bool ok2 = r2 < e;
        float4 v1;
        if (ok2) v1 = *(const float4*)(x + (size_t)r2 * D_FEAT + fb);
        {
            float f[4] = {v0.x, v0.y, v0.z, v0.w};
#pragma unroll
            for (int j = 0; j < 4; ++j) {
                sum[j] += f[j]; sq[j] += f[j] * f[j];
                mx[j] = fmaxf(mx[j], f[j]); mn[j] = fminf(mn[j], f[j]);
            }
        }
        if (ok2) {
            float f[4] = {v1.x, v1.y, v1.z, v1.w};
#pragma unroll
            for (int j = 0; j < 4; ++j) {
                sum[j] += f[j]; sq[j] += f[j] * f[j];
                mx[j] = fmaxf(mx[j], f[j]); mn[j] = fminf(mn[j], f[j]);
            }
        }
    }

    __shared__ float red[8][128];
    float rsum = 0.f, rsq = 0.f, rmx = -3.4e38f, rmn = 3.4e38f;

#pragma unroll
    for (int j = 0; j < 4; ++j) red[grp][fb + j] = sum[j];
    __syncthreads();
    if (t < 128) { for (int k = 0; k < 8; ++k) rsum += red[k][t]; }
    __syncthreads();
#pragma unroll
    for (int j = 0; j < 4; ++j) red[grp][fb + j] = sq[j];
    __syncthreads();
    if (t < 128) { for (int k = 0; k < 8; ++k) rsq += red[k][t]; }
    __syncthreads();
#pragma unroll
    for (int j = 0; j < 4; ++j) red[grp][fb + j] = mx[j];
    __syncthreads();
    if (t < 128) { for (int k = 0; k < 8; ++k) rmx = fmaxf(rmx, red[k][t]); }
    __syncthreads();
#pragma unroll
    for (int j = 0; j < 4; ++j) red[grp][fb + j] = mn[j];
    __syncthreads();
    if (t < 128) { for (int k = 0; k < 8; ++k) rmn = fminf(rmn, red[k][t]); }

    if (t < 128) {
        float cnt = (float)(e - s);
        float safe = fmaxf(cnt, 1.f);
        float mean = rsum / safe;
        float var = rsq / safe - mean * mean;
        float sd = sqrtf(fmaxf(var, 1e-5f));   // PyG Std: clamp then sqrt
        float vmx = (cnt > 0.f) ? rmx : 0.f;
        float vmn = (cnt > 0.f) ? rmn : 0.f;
        size_t base = (size_t)g * IN_DIM;
        packed[base + 64 + t]  = (bf16_t)mean;
        packed[base + 192 + t] = (bf16_t)sd;
        packed[base + 320 + t] = (bf16_t)vmx;
        packed[base + 448 + t] = (bf16_t)vmn;
    }
}

// ---------------------------------------------------------------------------
// mlp: fused GEMM1 (576->256) + bias + SELU + LayerNorm + GEMM2 (256->128)
// 512 blocks x 256 threads; each block = 16 graph rows.
// mfma_f32_16x16x32_bf16: A[m=lane&15][k=quad*8+j]; D: col=lane&15,
// row=quad*4+reg (verified layout). Output fp32.
// ---------------------------------------------------------------------------
__global__ __launch_bounds__(256) void mlp_kernel(
    const bf16_t* __restrict__ packed, const bf16_t* __restrict__ W1t,
    const float* __restrict__ b1, const float* __restrict__ ln_g,
    const float* __restrict__ ln_b, const bf16_t* __restrict__ W2t,
    const float* __restrict__ b2, float* __restrict__ out)
{
    int blk = blockIdx.x;
    int t = threadIdx.x;
    int wave = t >> 6, lane = t & 63;
    int l15 = lane & 15, quad = lane >> 4;
    int row0 = blk * 16;

    __shared__ float hbuf[16][HIDDEN];
    __shared__ bf16_t hbf[16][HIDDEN];

    // ---- GEMM1: wave w -> cols w*64..w*64+63 (4 mfma col-tiles), K=576 ----
    int c0 = wave * 64;
    f32x4 acc[4];
#pragma unroll
    for (int ct = 0; ct < 4; ++ct) acc[ct] = (f32x4){0.f, 0.f, 0.f, 0.f};

    const bf16_t* arow = packed + (size_t)(row0 + l15) * IN_DIM + quad * 8;
    for (int kk = 0; kk < IN_DIM; kk += 32) {
        bf16x8 a = __builtin_bit_cast(bf16x8, *(const uint4*)(arow + kk));
#pragma unroll
        for (int ct = 0; ct < 4; ++ct) {
            const bf16_t* bp = W1t + (size_t)(c0 + ct * 16 + l15) * IN_DIM + kk + quad * 8;
            bf16x8 b = __builtin_bit_cast(bf16x8, *(const uint4*)bp);
            acc[ct] = __builtin_amdgcn_mfma_f32_16x16x32_bf16(a, b, acc[ct], 0, 0, 0);
        }
    }

    const float SELU_SCALE = 1.0507009873554805f;
    const float SELU_ALPHA = 1.6732632423543772f;
#pragma unroll
    for (int ct = 0; ct < 4; ++ct) {
        int col = c0 + ct * 16 + l15;
        float bias = b1[col];
#pragma unroll
        for (int i = 0; i < 4; ++i) {
            int row = quad * 4 + i;
            float v = acc[ct][i] + bias;
            float pos = SELU_SCALE * v;
            float neg = SELU_SCALE * SELU_ALPHA * (__expf(v) - 1.f);
            hbuf[row][col] = (v > 0.f) ? pos : neg;
        }
    }
    __syncthreads();

    // ---- LayerNorm: 16 threads per row ----
    {
        int row = t >> 4, sub = t & 15;
        float s = 0.f, s2 = 0.f;
#pragma unroll
        for (int j = 0; j < 16; ++j) {
            float v = hbuf[row][sub * 16 + j];
            s += v; s2 += v * v;
        }
#pragma unroll
        for (int off = 8; off >= 1; off >>= 1) {
            s += __shfl_xor(s, off, 16);
            s2 += __shfl_xor(s2, off, 16);
        }
        float mu = s * (1.f / 256.f);
        float var = s2 * (1.f / 256.f) - mu * mu;
        float rstd = rsqrtf(var + 1e-5f);
#pragma unroll
        for (int j = 0; j < 16; ++j) {
            int c = sub * 16 + j;
            float v = (hbuf[row][c] - mu) * rstd * ln_g[c] + ln_b[c];
            hbf[row][c] = (bf16_t)v;
        }
    }
    __syncthreads();

    // ---- GEMM2: wave w -> cols w*32..w*32+31 (2 tiles), K=256 ----
    f32x4 acc2[2];
#pragma unroll
    for (int ct = 0; ct < 2; ++ct) acc2[ct] = (f32x4){0.f, 0.f, 0.f, 0.f};
    int c20 = wave * 32;
    for (int kk = 0; kk < HIDDEN; kk += 32) {
        bf16x8 a = *(const bf16x8*)(&hbf[l15][kk + quad * 8]);
#pragma unroll
        for (int ct = 0; ct < 2; ++ct) {
            const bf16_t* bp = W2t + (size_t)(c20 + ct * 16 + l15) * HIDDEN + kk + quad * 8;
            bf16x8 b = __builtin_bit_cast(bf16x8, *(const uint4*)bp);
            acc2[ct] = __builtin_amdgcn_mfma_f32_16x16x32_bf16(a, b, acc2[ct], 0, 0, 0);
        }
    }
#pragma unroll
    for (int ct = 0; ct < 2; ++ct) {
        int col = c20 + ct * 16 + l15;
        float bias = b2[col];
#pragma unroll
        for (int i = 0; i < 4; ++i) {
            int row = quad * 4 + i;
            out[(size_t)(row0 + row) * GDIM + col] = acc2[ct][i] + bias;
        }
    }
}

// ---------------------------------------------------------------------------
extern "C" void kernel_launch(void* const* d_in, const int* in_sizes, int n_in,
                              void* d_out, int out_size, void* d_ws, size_t ws_size,
                              hipStream_t stream)
{
    const float* x     = (const float*)d_in[0];
    const float* u     = (const float*)d_in[3];
    const int*   batch = (const int*)d_in[4];
    const float* W1    = (const float*)d_in[5];
    const float* b1    = (const float*)d_in[6];
    const float* ln_g  = (const float*)d_in[7];
    const float* ln_b  = (const float*)d_in[8];
    const float* W2    = (const float*)d_in[9];
    const float* b2    = (const float*)d_in[10];

    char* ws = (char*)d_ws;
    int*    starts = (int*)(ws + OFF_STARTS);
    bf16_t* packed = (bf16_t*)(ws + OFF_PACKED);
    bf16_t* W1t    = (bf16_t*)(ws + OFF_W1T);
    bf16_t* W2t    = (bf16_t*)(ws + OFF_W2T);

    prep_kernel<<<6659, 256, 0, stream>>>(u, batch, W1, W2, starts, packed, W1t, W2t);
    aggregate_kernel<<<N_GRAPHS, 256, 0, stream>>>(x, starts, packed);
    mlp_kernel<<<N_GRAPHS / 16, 256, 0, stream>>>(packed, W1t, b1, ln_g, ln_b, W2t, b2,
                                                  (float*)d_out);
}